// Round 4
// baseline (291.263 us; speedup 1.0000x reference)
//
#include <hip/hip_runtime.h>
#include <math.h>

#define VN 16
#define TN 2048
#define NROWS (VN*TN)   // 32768
#define DIN 64
#define HID 128
#define DKD 48
#define KNB 33
#define RROWS 8

// ---------------- Threefry-2x32, key = (0, 42) ----------------
__device__ __forceinline__ unsigned rotl32(unsigned x, int d){ return (x<<d)|(x>>(32-d)); }

// 20-round threefry2x32 on counter (c0, c1) with key (0, 42); returns (y0, y1)
__device__ __forceinline__ void tf2x32(unsigned c0, unsigned c1, unsigned& y0, unsigned& y1){
  const unsigned k0 = 0u, k1 = 42u;
  const unsigned k2 = k0 ^ k1 ^ 0x1BD11BDAu;
  unsigned x0 = c0, x1 = c1;
  x0 += k0; x1 += k1;
#define TF_R(r) { x0 += x1; x1 = rotl32(x1,(r)); x1 ^= x0; }
  TF_R(13) TF_R(15) TF_R(26) TF_R(6)   x0 += k1; x1 += k2 + 1u;
  TF_R(17) TF_R(29) TF_R(16) TF_R(24)  x0 += k2; x1 += k0 + 2u;
  TF_R(13) TF_R(15) TF_R(26) TF_R(6)   x0 += k0; x1 += k1 + 3u;
  TF_R(17) TF_R(29) TF_R(16) TF_R(24)  x0 += k1; x1 += k2 + 4u;
  TF_R(13) TF_R(15) TF_R(26) TF_R(6)   x0 += k2; x1 += k0 + 5u;
#undef TF_R
  y0 = x0; y1 = x1;
}

__global__ void jitter_kernel(const float* __restrict__ max_depth, double* __restrict__ md64){
  int n = blockIdx.x*blockDim.x + threadIdx.x;
  if (n >= NROWS) return;
  // np ref = reference() re-executed in float64 (x64 jax): uniform is FLOAT64,
  // partitionable threefry: 64-bit bits for element n come from ctr (hi=n>>32=0, lo=n).
  unsigned y0, y1;
  tf2x32(0u, (unsigned)n, y0, y1);
  unsigned long long bits = (((unsigned long long)y0) << 32) | (unsigned long long)y1;
  unsigned long long fb = (bits >> 12) | 0x3FF0000000000000ull;   // [1,2)
  double f;
  __builtin_memcpy(&f, &fb, 8);
  f -= 1.0;                                                       // U[0,1) f64
  md64[n] = (double)max_depth[n] + f * (1.0/8192.0);              // exact f64
}

// ---------------- q/k/v MLPs: 64 -> relu(128) -> 48, f64 accumulation ----------------
__global__ void qkv_kernel(const float* __restrict__ enc,
    const float* __restrict__ Wq1, const float* __restrict__ bq1,
    const float* __restrict__ Wq2, const float* __restrict__ bq2,
    const float* __restrict__ Wk1, const float* __restrict__ bk1,
    const float* __restrict__ Wk2, const float* __restrict__ bk2,
    const float* __restrict__ Wv1, const float* __restrict__ bv1,
    const float* __restrict__ Wv2, const float* __restrict__ bv2,
    float* __restrict__ qo, float* __restrict__ ko, float* __restrict__ vo)
{
  __shared__ float s_x[RROWS][DIN];
  __shared__ float s_h[RROWS][HID+1];
  int tid = threadIdx.x;              // 128 threads
  int base = blockIdx.x * RROWS;
  for (int i = tid; i < RROWS*DIN; i += 128){
    int r = i >> 6, c = i & 63;
    s_x[r][c] = enc[(base+r)*DIN + c];
  }
  __syncthreads();

  const float* W1s[3] = {Wq1, Wk1, Wv1};
  const float* b1s[3] = {bq1, bk1, bv1};
  const float* W2s[3] = {Wq2, Wk2, Wv2};
  const float* b2s[3] = {bq2, bk2, bv2};
  float* outs[3] = {qo, ko, vo};

  for (int mm = 0; mm < 3; mm++){
    double h[RROWS];
    double b1 = (double)b1s[mm][tid];
    #pragma unroll
    for (int r=0;r<RROWS;r++) h[r] = b1;
    for (int i=0;i<DIN;i++){
      double w = (double)W1s[mm][i*HID + tid];
      #pragma unroll
      for (int r=0;r<RROWS;r++) h[r] = fma((double)s_x[r][i], w, h[r]);
    }
    #pragma unroll
    for (int r=0;r<RROWS;r++) s_h[r][tid] = (float)fmax(h[r], 0.0);
    __syncthreads();
    if (tid < DKD){
      double o[RROWS];
      double b2 = (double)b2s[mm][tid];
      #pragma unroll
      for (int r=0;r<RROWS;r++) o[r] = b2;
      for (int i=0;i<HID;i++){
        double w = (double)W2s[mm][i*DKD + tid];
        #pragma unroll
        for (int r=0;r<RROWS;r++) o[r] = fma((double)s_h[r][i], w, o[r]);
      }
      #pragma unroll
      for (int r=0;r<RROWS;r++) outs[mm][(base+r)*DKD + tid] = (float)o[r];
    }
    __syncthreads();
  }
}

// ---------------- attention: 1 wave (64 lanes) per row, f64 math, f64-exact comp ----------------
__global__ void attn_kernel(const float* __restrict__ qv, const float* __restrict__ kv,
    const float* __restrict__ vv, const float* __restrict__ role_emb,
    const double* __restrict__ md,
    const int* __restrict__ prev_values, const int* __restrict__ next_values,
    const int* __restrict__ window_indices, const int* __restrict__ indices,
    const float* __restrict__ prev_mask, const float* __restrict__ next_mask,
    const float* __restrict__ window_mask,
    float* __restrict__ ctx_out)
{
  __shared__ float  s_q[DKD];
  __shared__ double s_p[KNB];
  __shared__ int    s_idx[KNB];
  int lane = threadIdx.x;
  int n = blockIdx.x;
  int vrow = n >> 11;        // T = 2048
  int t    = n & 2047;

  if (lane < DKD) s_q[lane] = qv[n*DKD + lane];
  __syncthreads();

  double sc = -INFINITY;
  if (lane < KNB){
    int idx, role; bool valid;
    if (lane < 16){
      int m = lane*TN + t;
      idx   = prev_values[m];
      role  = (vrow<<4) + lane;
      valid = (prev_mask[m] == 0.0f);
    } else if (lane < 32){
      int v2 = lane - 16;
      int m = v2*TN + t;
      bool comp = md[n] > md[m];     // f64-exact comparison (np-ref semantics)
      idx   = comp ? indices[m] : next_values[m];
      role  = 256 + (vrow<<4) + v2;
      valid = comp || (next_mask[m] == 0.0f);
    } else {
      idx   = window_indices[n];
      role  = 512 + vrow;
      valid = (window_mask[n] == 0.0f);
    }
    s_idx[lane] = idx;
    const float4* kp = reinterpret_cast<const float4*>(kv + (size_t)idx*DKD);
    const float4* rp = reinterpret_cast<const float4*>(role_emb + (size_t)role*DKD);
    double acc = 0.0;
    #pragma unroll
    for (int d4 = 0; d4 < DKD/4; d4++){
      float4 kk = kp[d4], rr = rp[d4];
      acc = fma((double)s_q[4*d4+0], (double)kk.x + (double)rr.x, acc);
      acc = fma((double)s_q[4*d4+1], (double)kk.y + (double)rr.y, acc);
      acc = fma((double)s_q[4*d4+2], (double)kk.z + (double)rr.z, acc);
      acc = fma((double)s_q[4*d4+3], (double)kk.w + (double)rr.w, acc);
    }
    sc = acc / sqrt(48.0);           // f64 scale
    if (!valid) sc = -1e9;
  }
  // wave softmax over lanes 0..32 (others hold -inf / contribute 0)
  double mx = sc;
  #pragma unroll
  for (int o=32;o>0;o>>=1) mx = fmax(mx, __shfl_xor(mx, o));
  double e = (lane < KNB) ? exp(sc - mx) : 0.0;
  double ssum = e;
  #pragma unroll
  for (int o=32;o>0;o>>=1) ssum += __shfl_xor(ssum, o);
  if (lane < KNB) s_p[lane] = e / ssum;
  __syncthreads();

  if (lane < DKD){
    double c = 0.0;
    for (int j=0;j<KNB;j++)
      c = fma(s_p[j], (double)vv[(size_t)s_idx[j]*DKD + lane], c);
    ctx_out[n*DKD + lane] = (float)c;
  }
}

// ---------------- heads: dp (112->128->2), mp (64->128->2), NLL in f64 ----------------
__device__ __forceinline__ double nlogp_d(double x, double mu, double ls){
  // softplus = logaddexp(ls, 0) = max(ls,0) + log1p(exp(-|ls|))
  double sp = fmax(ls, 0.0) + log1p(exp(-fabs(ls)));
  double s = sp + 1e-3;
  double z = (x - mu) / s;
  return 0.5*z*z + log(s) + 0.9189385332046727417803297; // 0.5*log(2*pi)
}

__global__ void heads_kernel(const float* __restrict__ enc, const float* __restrict__ ctx,
    const float* __restrict__ uu,
    const float* __restrict__ Wd1, const float* __restrict__ bd1,
    const float* __restrict__ Wd2, const float* __restrict__ bd2,
    const float* __restrict__ Wm1, const float* __restrict__ bm1,
    const float* __restrict__ Wm2, const float* __restrict__ bm2,
    float* __restrict__ out)
{
  __shared__ float s_x[RROWS][DIN+DKD];     // [8][112]
  __shared__ float s_hd[RROWS][HID+1];
  __shared__ float s_hm[RROWS][HID+1];
  __shared__ double s_o[RROWS][4];
  int tid = threadIdx.x;     // 128
  int base = blockIdx.x * RROWS;

  for (int i = tid; i < RROWS*DIN; i += 128){
    int r = i >> 6, c = i & 63;
    s_x[r][c] = enc[(base+r)*DIN + c];
  }
  for (int i = tid; i < RROWS*DKD; i += 128){
    int r = i / DKD, c = i - r*DKD;
    s_x[r][DIN + c] = ctx[(base+r)*DKD + c];
  }
  __syncthreads();

  double h[RROWS];
  // dp hidden: 112 -> 128
  {
    double b = (double)bd1[tid];
    #pragma unroll
    for (int r=0;r<RROWS;r++) h[r] = b;
    for (int i=0;i<DIN+DKD;i++){
      double w = (double)Wd1[i*HID + tid];
      #pragma unroll
      for (int r=0;r<RROWS;r++) h[r] = fma((double)s_x[r][i], w, h[r]);
    }
    #pragma unroll
    for (int r=0;r<RROWS;r++) s_hd[r][tid] = (float)fmax(h[r], 0.0);
  }
  // mp hidden: 64 -> 128
  {
    double b = (double)bm1[tid];
    #pragma unroll
    for (int r=0;r<RROWS;r++) h[r] = b;
    for (int i=0;i<DIN;i++){
      double w = (double)Wm1[i*HID + tid];
      #pragma unroll
      for (int r=0;r<RROWS;r++) h[r] = fma((double)s_x[r][i], w, h[r]);
    }
    #pragma unroll
    for (int r=0;r<RROWS;r++) s_hm[r][tid] = (float)fmax(h[r], 0.0);
  }
  __syncthreads();

  if (tid < 32){
    int r     = tid >> 2;
    int which = (tid >> 1) & 1;   // 0: dp, 1: mp
    int o     = tid & 1;
    const float* hh = which ? s_hm[r] : s_hd[r];
    const float* W2 = which ? Wm2 : Wd2;
    double acc = (double)(which ? bm2[o] : bd2[o]);
    for (int i=0;i<HID;i++) acc = fma((double)hh[i], (double)W2[i*2 + o], acc);
    s_o[r][which*2 + o] = acc;
  }
  __syncthreads();

  if (tid < RROWS){
    int n = base + tid;
    double x = (double)uu[n];
    out[n] = (float)(nlogp_d(x, s_o[tid][0], s_o[tid][1]) +
                     nlogp_d(x, s_o[tid][2], s_o[tid][3]));
  }
}

extern "C" void kernel_launch(void* const* d_in, const int* in_sizes, int n_in,
                              void* d_out, int out_size, void* d_ws, size_t ws_size,
                              hipStream_t stream) {
  const float* encoded = (const float*)d_in[0];
  const float* u       = (const float*)d_in[1];
  const float* Wq1 = (const float*)d_in[2];  const float* bq1 = (const float*)d_in[3];
  const float* Wq2 = (const float*)d_in[4];  const float* bq2 = (const float*)d_in[5];
  const float* Wk1 = (const float*)d_in[6];  const float* bk1 = (const float*)d_in[7];
  const float* Wk2 = (const float*)d_in[8];  const float* bk2 = (const float*)d_in[9];
  const float* Wv1 = (const float*)d_in[10]; const float* bv1 = (const float*)d_in[11];
  const float* Wv2 = (const float*)d_in[12]; const float* bv2 = (const float*)d_in[13];
  const float* role_emb = (const float*)d_in[14];
  const float* Wd1 = (const float*)d_in[15]; const float* bd1 = (const float*)d_in[16];
  const float* Wd2 = (const float*)d_in[17]; const float* bd2 = (const float*)d_in[18];
  const float* Wm1 = (const float*)d_in[19]; const float* bm1 = (const float*)d_in[20];
  const float* Wm2 = (const float*)d_in[21]; const float* bm2 = (const float*)d_in[22];
  const int*   prev_values    = (const int*)d_in[23];
  const int*   next_values    = (const int*)d_in[24];
  const int*   window_indices = (const int*)d_in[25];
  const int*   indices        = (const int*)d_in[26];
  const float* prev_mask   = (const float*)d_in[27];
  const float* next_mask   = (const float*)d_in[28];
  const float* window_mask = (const float*)d_in[29];
  const float* max_depth   = (const float*)d_in[30];
  float* out = (float*)d_out;

  double* md64 = (double*)d_ws;                       // 32768 doubles
  float* q  = (float*)(md64 + NROWS);
  float* k  = q  + (size_t)NROWS*DKD;
  float* v  = k  + (size_t)NROWS*DKD;
  float* cx = v  + (size_t)NROWS*DKD;

  jitter_kernel<<<(NROWS+255)/256, 256, 0, stream>>>(max_depth, md64);
  qkv_kernel<<<NROWS/RROWS, 128, 0, stream>>>(encoded,
      Wq1,bq1,Wq2,bq2, Wk1,bk1,Wk2,bk2, Wv1,bv1,Wv2,bv2, q, k, v);
  attn_kernel<<<NROWS, 64, 0, stream>>>(q, k, v, role_emb, md64,
      prev_values, next_values, window_indices, indices,
      prev_mask, next_mask, window_mask, cx);
  heads_kernel<<<NROWS/RROWS, 128, 0, stream>>>(encoded, cx, u,
      Wd1,bd1,Wd2,bd2, Wm1,bm1,Wm2,bm2, out);
}